// Round 7
// baseline (1853.226 us; speedup 1.0000x reference)
//
#include <hip/hip_runtime.h>
#include <hip/hip_bf16.h>

typedef short short8  __attribute__((ext_vector_type(8)));
typedef float floatx4 __attribute__((ext_vector_type(4)));
typedef int   int4v   __attribute__((ext_vector_type(4)));

constexpr int BB = 64, PP = 196, CENC = 2048, HH = 512, AA = 512, EE = 512;
constexpr int VV = 10000, TT = 20, TM1 = 19;

__device__ __forceinline__ float bf2f(short u) {
    union { unsigned u; float f; } v; v.u = ((unsigned)(unsigned short)u) << 16; return v.f;
}
__device__ __forceinline__ short f2bf(float f) {
    union { float f; unsigned u; } v; v.f = f;
    unsigned r = v.u + 0x7FFF + ((v.u >> 16) & 1);
    return (short)(r >> 16);
}

// async global->LDS, 16B per lane; LDS dest = wave-uniform base + lane*16
#define GLL(gp, lp) __builtin_amdgcn_global_load_lds( \
    (const __attribute__((address_space(1))) void*)(gp), \
    (__attribute__((address_space(3))) void*)(lp), 16, 0, 0)

// ---------------------------------------------------------------------------
// Weight prep. Element segments (8 elems/thread):
//  [0,        1048576): encw16  <- enc_att_w [512][2048]
//  [1048576,  3145728): wcat16  <- [fbeta_w(2048) ; w_hh(2048)] x 512
//  [3145728,  7340032): wihe16  <- w_ih[:, 512:] [2048][2048]
//  [7340032,  8388608): wihm16  <- w_ih[:, :512] [2048][512]
//  [8388608, 13508608): fc16    <- fc_w [10000][512]
//  [13508608,15605760): initW16 <- [init_h_w ; init_c_w] [1024][2048]
//  [15605760,15867904): hidattT <- hid_att_w^T [512 k][512 a]
//  [15867904,15872000): biascat (f32 4096) = [fbeta_b ; 0]
//  [15872000,15874048): biasg   (f32 2048) = b_ih + b_hh
//  [15874048,15875072): biasInit(f32 1024) = [init_h_b ; init_c_b]
// ---------------------------------------------------------------------------
__global__ __launch_bounds__(256)
void kPrepW(const float* __restrict__ encw_s, const float* __restrict__ haw,
            const float* __restrict__ fbw, const float* __restrict__ whh,
            const float* __restrict__ wih, const float* __restrict__ fcw,
            const float* __restrict__ ihw, const float* __restrict__ icw,
            const float* __restrict__ fbb, const float* __restrict__ bih,
            const float* __restrict__ bhh, const float* __restrict__ ihb,
            const float* __restrict__ icb,
            short* __restrict__ encw_d, short* __restrict__ wcat_d,
            short* __restrict__ wihe_d, short* __restrict__ wihm_d,
            short* __restrict__ fc_d, short* __restrict__ initW_d,
            short* __restrict__ hidattT, float* __restrict__ biascat,
            float* __restrict__ biasg, float* __restrict__ biasInit)
{
    long e = ((long)blockIdx.x * 256 + threadIdx.x) * 8;
    union { short s[8]; int4v v; } u8;
    const float* sp = nullptr; short* dp = nullptr; long de = 0;
    if (e < 1048576)       { sp = &encw_s[e]; dp = encw_d; de = e; }
    else if (e < 3145728)  { long u = e - 1048576; long row = u >> 9, col = u & 511;
                             sp = (row < 2048) ? &fbw[row * 512 + col]
                                               : &whh[(row - 2048) * 512 + col];
                             dp = wcat_d; de = u; }
    else if (e < 7340032)  { long u = e - 3145728; long row = u >> 11, col = u & 2047;
                             sp = &wih[row * 2560 + 512 + col]; dp = wihe_d; de = u; }
    else if (e < 8388608)  { long u = e - 7340032; long row = u >> 9, col = u & 511;
                             sp = &wih[row * 2560 + col]; dp = wihm_d; de = u; }
    else if (e < 13508608) { long u = e - 8388608; sp = &fcw[u]; dp = fc_d; de = u; }
    else if (e < 15605760) { long u = e - 13508608;
                             sp = (u < 1048576) ? &ihw[u] : &icw[u - 1048576];
                             dp = initW_d; de = u; }
    else if (e < 15867904) { long u = e - 15605760; long k = u >> 9, a0 = u & 511;
                             #pragma unroll
                             for (int j = 0; j < 8; ++j) u8.s[j] = f2bf(haw[(a0 + j) * 512 + k]);
                             *reinterpret_cast<int4v*>(&hidattT[u]) = u8.v;
                             return; }
    else if (e < 15872000) { long u = e - 15867904;
                             for (int j = 0; j < 8; ++j) { long w = u + j;
                                 biascat[w] = (w < 2048) ? fbb[w] : 0.f; }
                             return; }
    else if (e < 15874048) { long u = e - 15872000;
                             for (int j = 0; j < 8; ++j) biasg[u + j] = bih[u + j] + bhh[u + j];
                             return; }
    else if (e < 15875072) { long u = e - 15874048;
                             for (int j = 0; j < 8; ++j) { long w = u + j;
                                 biasInit[w] = (w < 512) ? ihb[w] : icb[w - 512]; }
                             return; }
    else return;
    #pragma unroll
    for (int j = 0; j < 8; ++j) u8.s[j] = f2bf(sp[j]);
    *reinterpret_cast<int4v*>(&dp[de]) = u8.v;
}

// p-split mean partials + enc f32->bf16. grid (64, 8, 7): 28 rows per z-block.
template<int FULL>
__global__ __launch_bounds__(256)
void kMeanEnc(const float* __restrict__ enc, short* __restrict__ enc16,
              float* __restrict__ meanP)
{
    int b = blockIdx.x, kc = blockIdx.y, pz = blockIdx.z;
    int k = kc * 256 + threadIdx.x;
    const float* eb = &enc[((size_t)b * PP + pz * 28) * CENC + k];
    short* ob = &enc16[((size_t)b * PP + pz * 28) * CENC + k];
    float s0 = 0, s1 = 0, s2 = 0, s3 = 0;
    for (int p = 0; p < 28; p += 4) {
        float v0 = eb[(size_t)(p + 0) * CENC], v1 = eb[(size_t)(p + 1) * CENC];
        float v2 = eb[(size_t)(p + 2) * CENC], v3 = eb[(size_t)(p + 3) * CENC];
        s0 += v0; s1 += v1; s2 += v2; s3 += v3;
        if (FULL) {
            ob[(size_t)(p + 0) * CENC] = f2bf(v0); ob[(size_t)(p + 1) * CENC] = f2bf(v1);
            ob[(size_t)(p + 2) * CENC] = f2bf(v2); ob[(size_t)(p + 3) * CENC] = f2bf(v3);
        }
    }
    meanP[((size_t)pz * 64 + b) * 2048 + k] = (s0 + s1) + (s2 + s3);
}

// reduce 7 meanP partials -> mean16 bf16 [64][2048]
__global__ __launch_bounds__(256)
void kReduceMean(const float* __restrict__ meanP, short* __restrict__ mean16)
{
    int b = blockIdx.x, c0 = threadIdx.x * 8;
    const float inv = 1.0f / PP;
    union { short s[8]; int4v v; } u8;
    #pragma unroll
    for (int j = 0; j < 8; ++j) {
        float s = 0.f;
        #pragma unroll
        for (int pz = 0; pz < 7; ++pz) s += meanP[((size_t)pz * 64 + b) * 2048 + c0 + j];
        u8.s[j] = f2bf(s * inv);
    }
    *reinterpret_cast<int4v*>(&mean16[b * 2048 + c0]) = u8.v;
}

// embedding gather -> embA[r = t*64+b][512] bf16
__global__ __launch_bounds__(256)
void kEmbGather(const float* __restrict__ embw, const int* __restrict__ captions,
                short* __restrict__ embA)
{
    long e = ((long)blockIdx.x * 256 + threadIdx.x) * 8;
    int r = (int)(e >> 9), j = (int)(e & 511);
    int t = r >> 6, b = r & 63;
    int tok = captions[b * TT + t];
    const float* sp = &embw[(size_t)tok * EE + j];
    union { short s[8]; int4v v; } u8;
    #pragma unroll
    for (int q = 0; q < 8; ++q) u8.s[q] = f2bf(sp[q]);
    *reinterpret_cast<int4v*>(&embA[e]) = u8.v;
}

// ---------------------------------------------------------------------------
// 64-tile MFMA GEMM (small/medium GEMMs): C[M,N] = A[M,K] @ W[N,K]^T.
// EOP: 0 = f32 +bias; 3 = plain k-partials
// ---------------------------------------------------------------------------
template<int EOP>
__global__ __launch_bounds__(256)
void kGemm(const short* __restrict__ A, int lda, const short* __restrict__ W, int ldw,
           const float* __restrict__ bias,
           float* __restrict__ outF, int ldc, int nk)
{
    __shared__ short As[64 * 64];
    __shared__ short Ws[64 * 64];
    const int nb = blockIdx.x, mb = blockIdx.y, kz = blockIdx.z;
    const int tid = threadIdx.x;
    const int m0 = mb * 64, n0 = nb * 64, k0 = kz * nk * 64;
    const int w = tid >> 6, l = tid & 63;
    floatx4 acc[4] = {};

    for (int ks = 0; ks < nk; ++ks) {
        int kt = k0 + ks * 64;
        #pragma unroll
        for (int i = 0; i < 2; ++i) {
            int ii = w * 2 + i;
            int row = ii * 8 + (l >> 3), cg = l & 7;
            GLL(&A[(size_t)(m0 + row) * lda + kt + ((cg ^ (row & 7)) << 3)], &As[ii * 512]);
        }
        #pragma unroll
        for (int i = 0; i < 2; ++i) {
            int ii = w * 2 + i;
            int r = ii * 8 + (l >> 3), cg = l & 7;
            GLL(&W[(size_t)(n0 + r) * ldw + kt + ((cg ^ (r & 7)) << 3)], &Ws[ii * 512]);
        }
        __syncthreads();
        #pragma unroll
        for (int kc = 0; kc < 2; ++kc) {
            int arow = 16 * w + (l & 15);
            int cg = 4 * kc + (l >> 4);
            short8 af = *reinterpret_cast<const short8*>(&As[arow * 64 + ((cg ^ (arow & 7)) << 3)]);
            #pragma unroll
            for (int q = 0; q < 4; ++q) {
                int wrow = 16 * q + (l & 15);
                short8 wf = *reinterpret_cast<const short8*>(&Ws[wrow * 64 + ((cg ^ (wrow & 7)) << 3)]);
                acc[q] = __builtin_amdgcn_mfma_f32_16x16x32_bf16(af, wf, acc[q], 0, 0, 0);
            }
        }
        __syncthreads();
    }
    int l4 = l >> 4, l15 = l & 15;
    #pragma unroll
    for (int q = 0; q < 4; ++q) {
        #pragma unroll
        for (int j = 0; j < 4; ++j) {
            int m = m0 + 16 * w + 4 * l4 + j;
            int n = n0 + 16 * q + l15;
            float val = acc[q][j];
            if (EOP == 0) {
                outF[(size_t)m * ldc + n] = val + bias[n];
            } else {  // plain k-partials
                int mloc = m - m0;
                outF[((size_t)kz * 64 + mloc) * ldc + n] = val;
            }
        }
    }
}

// ---------------------------------------------------------------------------
// 128x128-tile MFMA GEMM (att1 / pred). BK=64, 4 waves, wave owns 32 rows.
// AOP: 0 = A bf16 (gll); 1 = A f32 (register convert)
// EOP: 1 = bf16 out +bias; 2 = pred f32 (mask/remap, bounds)
// SWZ: 1 = att1 (392 blk, 8x49); 2 = pred (790 blk, bijective)
// NOTE: A/W tiles may over-read past M/N bounds (benign: adjacent scratch);
//       stores are masked.
// ---------------------------------------------------------------------------
template<int AOP, int EOP, int SWZ>
__global__ __launch_bounds__(256)
void kGemm128(const void* __restrict__ Ap, int lda, const short* __restrict__ W, int ldw,
              const float* __restrict__ bias, int Ntot, int Mtot,
              float* __restrict__ outF, short* __restrict__ outB, int ldc,
              int nk, const int* __restrict__ lengths)
{
    __shared__ short As[128 * 64];
    __shared__ short Ws[128 * 64];
    int mb, nb;
    if (SWZ == 1) {            // 392 = 8 x 49; same-mb quads per XCD
        int o = blockIdx.x;
        int wg = (o & 7) * 49 + (o >> 3);
        mb = wg >> 2; nb = wg & 3;
    } else {                   // 790 = 6x99 + 2x98 (m204 bijective)
        int o = blockIdx.x;
        int x = o & 7, idx = o >> 3;
        int base = (x < 6) ? x * 99 : 594 + (x - 6) * 98;
        int wg = base + idx;
        mb = wg % 10; nb = wg / 10;
    }
    const int tid = threadIdx.x, w = tid >> 6, l = tid & 63;
    const int m0 = mb * 128, n0 = nb * 128;
    const int l4 = l >> 4, l15 = l & 15;
    floatx4 acc[2][8] = {};

    for (int ks = 0; ks < nk; ++ks) {
        int kt = ks * 64;
        if (AOP == 0) {
            const short* A = (const short*)Ap;
            #pragma unroll
            for (int i = 0; i < 4; ++i) {
                int ii = w * 4 + i;
                int row = ii * 8 + (l >> 3), cg = l & 7;
                GLL(&A[(size_t)(m0 + row) * lda + kt + ((cg ^ (row & 7)) << 3)], &As[ii * 512]);
            }
        } else {
            const float* A = (const float*)Ap;
            #pragma unroll
            for (int i = 0; i < 4; ++i) {
                int s = tid + i * 256, row = s >> 3, cg = s & 7;
                const float* sp = &A[(size_t)(m0 + row) * lda + kt + cg * 8];
                float4 a = *reinterpret_cast<const float4*>(sp);
                float4 b = *reinterpret_cast<const float4*>(sp + 4);
                union { short s[8]; int4v v; } u8;
                u8.s[0]=f2bf(a.x); u8.s[1]=f2bf(a.y); u8.s[2]=f2bf(a.z); u8.s[3]=f2bf(a.w);
                u8.s[4]=f2bf(b.x); u8.s[5]=f2bf(b.y); u8.s[6]=f2bf(b.z); u8.s[7]=f2bf(b.w);
                *reinterpret_cast<int4v*>(&As[row * 64 + ((cg ^ (row & 7)) << 3)]) = u8.v;
            }
        }
        #pragma unroll
        for (int i = 0; i < 4; ++i) {
            int ii = w * 4 + i;
            int r = ii * 8 + (l >> 3), cg = l & 7;
            GLL(&W[(size_t)(n0 + r) * ldw + kt + ((cg ^ (r & 7)) << 3)], &Ws[ii * 512]);
        }
        __syncthreads();
        #pragma unroll
        for (int kc = 0; kc < 2; ++kc) {
            int cg = 4 * kc + l4;
            short8 af0, af1;
            {
                int ar0 = 32 * w + l15;
                int ar1 = 32 * w + 16 + l15;
                af0 = *reinterpret_cast<const short8*>(&As[ar0 * 64 + ((cg ^ (ar0 & 7)) << 3)]);
                af1 = *reinterpret_cast<const short8*>(&As[ar1 * 64 + ((cg ^ (ar1 & 7)) << 3)]);
            }
            #pragma unroll
            for (int q = 0; q < 8; ++q) {
                int wrow = 16 * q + l15;
                short8 wf = *reinterpret_cast<const short8*>(&Ws[wrow * 64 + ((cg ^ (wrow & 7)) << 3)]);
                acc[0][q] = __builtin_amdgcn_mfma_f32_16x16x32_bf16(af0, wf, acc[0][q], 0, 0, 0);
                acc[1][q] = __builtin_amdgcn_mfma_f32_16x16x32_bf16(af1, wf, acc[1][q], 0, 0, 0);
            }
        }
        __syncthreads();
    }
    #pragma unroll
    for (int sm = 0; sm < 2; ++sm) {
        #pragma unroll
        for (int q = 0; q < 8; ++q) {
            #pragma unroll
            for (int j = 0; j < 4; ++j) {
                int m = m0 + 32 * w + 16 * sm + 4 * l4 + j;
                int n = n0 + 16 * q + l15;
                float val = acc[sm][q][j];
                if (EOP == 1) {
                    outB[(size_t)m * ldc + n] = f2bf(val + bias[n]);
                } else {
                    if (m < Mtot && n < Ntot) {
                        int b = m & 63, tt = m >> 6;
                        bool act = tt < (lengths[b] - 1);
                        outF[((size_t)b * TM1 + tt) * VV + n] = act ? (val + bias[n]) : 0.f;
                    }
                }
            }
        }
    }
}

__global__ __launch_bounds__(256)
void kReduceHC(const float* __restrict__ Pc, const float* __restrict__ biasInit,
               float* __restrict__ hc, short* __restrict__ h16)
{
    int b = blockIdx.x, tid = threadIdx.x;
    for (int j = tid; j < 1024; j += 256) {
        float s = Pc[((size_t)0 * BB + b) * 1024 + j] + Pc[((size_t)1 * BB + b) * 1024 + j]
                + Pc[((size_t)2 * BB + b) * 1024 + j] + Pc[((size_t)3 * BB + b) * 1024 + j];
        s += biasInit[j];
        hc[b * 1024 + j] = s;
        if (j < 512) h16[b * 512 + j] = f2bf(s);
    }
}

// ---------------------------------------------------------------------------
// K1 (128 blocks x 256): blocks 0..63 = P3h GEMM (N=4096: [fbeta|whh], K=512);
// blocks 64..127 = per-b attention: att2 = h @ hid_att_w^T (redundant matvec),
// e = relu(att1+att2)@faw + fab, softmax -> alphaG + masked out_alpha.
// ---------------------------------------------------------------------------
__global__ __launch_bounds__(256)
void kStepA(const short* __restrict__ h16, const short* __restrict__ wcat16,
            const float* __restrict__ biascat, const short* __restrict__ hidattT,
            const float* __restrict__ hid_att_b, const short* __restrict__ att1,
            const float* __restrict__ faw, const float* __restrict__ fab,
            const int* __restrict__ lengths, float* __restrict__ P3h,
            float* __restrict__ alphaG, float* __restrict__ out_alpha, int t)
{
    __shared__ __align__(16) char smem[16384];
    const int blk = blockIdx.x, tid = threadIdx.x;
    const int w = tid >> 6, l = tid & 63;

    if (blk < 64) {
        short* As = (short*)smem;
        short* Ws = (short*)(smem + 8192);
        const int n0 = blk * 64;
        floatx4 acc[4] = {};
        for (int ks = 0; ks < 8; ++ks) {
            int kt = ks * 64;
            #pragma unroll
            for (int i = 0; i < 2; ++i) {
                int ii = w * 2 + i;
                int row = ii * 8 + (l >> 3), cg = l & 7;
                GLL(&h16[row * 512 + kt + ((cg ^ (row & 7)) << 3)], &As[ii * 512]);
            }
            #pragma unroll
            for (int i = 0; i < 2; ++i) {
                int ii = w * 2 + i;
                int r = ii * 8 + (l >> 3), cg = l & 7;
                GLL(&wcat16[(size_t)(n0 + r) * 512 + kt + ((cg ^ (r & 7)) << 3)], &Ws[ii * 512]);
            }
            __syncthreads();
            #pragma unroll
            for (int kc = 0; kc < 2; ++kc) {
                int arow = 16 * w + (l & 15);
                int cg = 4 * kc + (l >> 4);
                short8 af = *reinterpret_cast<const short8*>(&As[arow * 64 + ((cg ^ (arow & 7)) << 3)]);
                #pragma unroll
                for (int q = 0; q < 4; ++q) {
                    int wrow = 16 * q + (l & 15);
                    short8 wf = *reinterpret_cast<const short8*>(&Ws[wrow * 64 + ((cg ^ (wrow & 7)) << 3)]);
                    acc[q] = __builtin_amdgcn_mfma_f32_16x16x32_bf16(af, wf, acc[q], 0, 0, 0);
                }
            }
            __syncthreads();
        }
        int l4 = l >> 4, l15 = l & 15;
        #pragma unroll
        for (int q = 0; q < 4; ++q)
            #pragma unroll
            for (int j = 0; j < 4; ++j) {
                int m = 16 * w + 4 * l4 + j;
                int n = n0 + 16 * q + l15;
                P3h[m * 4096 + n] = acc[q][j] + biascat[n];
            }
    } else {
        const int b = blk - 64;
        float* hsh   = (float*)smem;            // 512
        float* att2s = (float*)(smem + 2048);   // 512
        float* fwsh  = (float*)(smem + 4096);   // 512
        float* es    = (float*)(smem + 6144);   // 200
        float* red   = (float*)(smem + 7040);   // 8

        hsh[tid]       = bf2f(h16[b * 512 + tid]);
        hsh[tid + 256] = bf2f(h16[b * 512 + tid + 256]);
        fwsh[tid]       = faw[tid];
        fwsh[tid + 256] = faw[tid + 256];
        __syncthreads();

        // att2 = hid_att_b + h @ hidattT (each thread: cols tid, tid+256)
        {
            float s0 = hid_att_b[tid], s1 = hid_att_b[tid + 256];
            for (int k = 0; k < 512; k += 8) {
                #pragma unroll
                for (int j = 0; j < 8; ++j) {
                    float hk = hsh[k + j];
                    s0 = fmaf(bf2f(hidattT[(k + j) * 512 + tid]), hk, s0);
                    s1 = fmaf(bf2f(hidattT[(k + j) * 512 + tid + 256]), hk, s1);
                }
            }
            att2s[tid] = s0; att2s[tid + 256] = s1;
        }
        __syncthreads();

        for (int p = w; p < PP; p += 4) {
            short8 v = *reinterpret_cast<const short8*>(&att1[((size_t)b * PP + p) * 512 + l * 8]);
            float s = 0.f;
            #pragma unroll
            for (int j = 0; j < 8; ++j) {
                float x = bf2f(v[j]) + att2s[l * 8 + j];
                s += fmaxf(x, 0.f) * fwsh[l * 8 + j];
            }
            #pragma unroll
            for (int off = 32; off > 0; off >>= 1) s += __shfl_down(s, off, 64);
            if (l == 0) es[p] = s + fab[0];
        }
        __syncthreads();
        float m = -1e30f;
        for (int p = tid; p < PP; p += 256) m = fmaxf(m, es[p]);
        #pragma unroll
        for (int off = 32; off > 0; off >>= 1) m = fmaxf(m, __shfl_down(m, off, 64));
        if (l == 0) red[w] = m;
        __syncthreads();
        m = fmaxf(fmaxf(red[0], red[1]), fmaxf(red[2], red[3]));
        float ssum = 0.f;
        for (int p = tid; p < PP; p += 256) { float ev = __expf(es[p] - m); es[p] = ev; ssum += ev; }
        #pragma unroll
        for (int off = 32; off > 0; off >>= 1) ssum += __shfl_down(ssum, off, 64);
        if (l == 0) red[4 + w] = ssum;
        __syncthreads();
        float inv = 1.f / (red[4] + red[5] + red[6] + red[7]);
        bool active = t < (lengths[b] - 1);
        for (int p = tid; p < PP; p += 256) {
            float al = es[p] * inv;
            alphaG[b * PP + p] = al;
            out_alpha[((size_t)b * TM1 + t) * PP + p] = active ? al : 0.f;
        }
    }
}

// ---------------------------------------------------------------------------
// K2 (512 blocks: b = blk&63, kc = blk>>6): awe slice = alpha @ enc[b],
// x16 = sigmoid(P3h fbeta part) * awe.
// ---------------------------------------------------------------------------
template<int FULL>
__global__ __launch_bounds__(256)
void kStepC(const float* __restrict__ alphaG, const float* __restrict__ P3h,
            const void* __restrict__ encp, short* __restrict__ x16)
{
    int blk = blockIdx.x, tid = threadIdx.x;
    int b = blk & 63, kc = blk >> 6;
    __shared__ float alps[PP];
    __shared__ float part[8][256];
    for (int p = tid; p < PP; p += 256) alps[p] = alphaG[b * PP + p];
    __syncthreads();

    if (FULL) {
        const short* enc16 = (const short*)encp;
        int g = tid & 31, prow = tid >> 5;
        int k0 = kc * 256 + g * 8;
        float acc[8] = {};
        for (int p = prow; p < PP; p += 8) {
            short8 v = *reinterpret_cast<const short8*>(&enc16[((size_t)b * PP + p) * CENC + k0]);
            float a_ = alps[p];
            #pragma unroll
            for (int j = 0; j < 8; ++j) acc[j] = fmaf(bf2f(v[j]), a_, acc[j]);
        }
        *reinterpret_cast<float4*>(&part[prow][g * 8])     = make_float4(acc[0], acc[1], acc[2], acc[3]);
        *reinterpret_cast<float4*>(&part[prow][g * 8 + 4]) = make_float4(acc[4], acc[5], acc[6], acc[7]);
        __syncthreads();
        int c = tid;
        float awe = 0.f;
        #pragma unroll
        for (int pr = 0; pr < 8; ++pr) awe += part[pr][c];
        int k = kc * 256 + c;
        float gate = 1.f / (1.f + __expf(-P3h[b * 4096 + k]));
        x16[(size_t)b * CENC + k] = f2bf(gate * awe);
    } else {
        const float* enc = (const float*)encp;
        int g = tid & 63, prow = tid >> 6;
        int k0 = kc * 256 + g * 4;
        float acc[4] = {};
        for (int p = prow; p < PP; p += 4) {
            float4 v = *reinterpret_cast<const float4*>(&enc[((size_t)b * PP + p) * CENC + k0]);
            float a_ = alps[p];
            acc[0] = fmaf(v.x, a_, acc[0]); acc[1] = fmaf(v.y, a_, acc[1]);
            acc[2] = fmaf(v.z, a_, acc[2]); acc[3] = fmaf(v.w, a_, acc[3]);
        }
        *reinterpret_cast<float4*>(&part[prow][g * 4]) = make_float4(acc[0], acc[1], acc[2], acc[3]);
        __syncthreads();
        int c = tid;
        float awe = part[0][c] + part[1][c] + part[2][c] + part[3][c];
        int k = kc * 256 + c;
        float gate = 1.f / (1.f + __expf(-P3h[b * 4096 + k]));
        x16[(size_t)b * CENC + k] = f2bf(gate * awe);
    }
}

// ---------------------------------------------------------------------------
// K3 (32 blocks x 256): gates GEMM x16[64][2048] @ wihe16 (gate-interleaved
// rows), K=2048 full; LSTM cell fused in the epilogue.
// ---------------------------------------------------------------------------
__global__ __launch_bounds__(256)
void kStepD(const short* __restrict__ x16, const short* __restrict__ wihe16,
            const float* __restrict__ P3h, const float* __restrict__ gates_emb,
            float* __restrict__ hc, short* __restrict__ h16,
            short* __restrict__ allH, int t)
{
    __shared__ short As[64 * 64];
    __shared__ short Ws[64 * 64];
    const int nb = blockIdx.x, tid = threadIdx.x;
    const int w = tid >> 6, l = tid & 63;
    const int l4 = l >> 4, l15 = l & 15;
    floatx4 acc[4] = {};

    for (int ks = 0; ks < 32; ++ks) {
        int kt = ks * 64;
        #pragma unroll
        for (int i = 0; i < 2; ++i) {
            int ii = w * 2 + i;
            int row = ii * 8 + (l >> 3), cg = l & 7;
            GLL(&x16[row * 2048 + kt + ((cg ^ (row & 7)) << 3)], &As[ii * 512]);
        }
        #pragma unroll
        for (int i = 0; i < 2; ++i) {
            int ii = w * 2 + i;
            int r = ii * 8 + (l >> 3), cg = l & 7;
            int wr = 512 * (r >> 4) + 16 * nb + (r & 15);
            GLL(&wihe16[(size_t)wr * 2048 + kt + ((cg ^ (r & 7)) << 3)], &Ws[ii * 512]);
        }
        __syncthreads();
        #pragma unroll
        for (int kc = 0; kc < 2; ++kc) {
            int arow = 16 * w + l15;
            int cg = 4 * kc + l4;
            short8 af = *reinterpret_cast<const short8*>(&As[arow * 64 + ((cg ^ (arow & 7)) << 3)]);
            #pragma unroll
            for (int q = 0; q < 4; ++q) {
                int wrow = 16 * q + l15;
                short8 wf = *reinterpret_cast<const short8*>(&Ws[wrow * 64 + ((cg ^ (wrow & 7)) << 3)]);
                acc[q] = __builtin_amdgcn_mfma_f32_16x16x32_bf16(af, wf, acc[q], 0, 0, 0);
            }
        }
        __syncthreads();
    }

    const int d = 16 * nb + l15;
    #pragma unroll
    for (int j = 0; j < 4; ++j) {
        int m = 16 * w + 4 * l4 + j;
        float g0 = acc[0][j] + gates_emb[((size_t)t * 64 + m) * 2048 +    0 + d] + P3h[m * 4096 + 2048 +    0 + d];
        float g1 = acc[1][j] + gates_emb[((size_t)t * 64 + m) * 2048 +  512 + d] + P3h[m * 4096 + 2048 +  512 + d];
        float g2 = acc[2][j] + gates_emb[((size_t)t * 64 + m) * 2048 + 1024 + d] + P3h[m * 4096 + 2048 + 1024 + d];
        float g3 = acc[3][j] + gates_emb[((size_t)t * 64 + m) * 2048 + 1536 + d] + P3h[m * 4096 + 2048 + 1536 + d];
        float i_ = 1.f / (1.f + __expf(-g0));
        float f_ = 1.f / (1.f + __expf(-g1));
        float gg = tanhf(g2);
        float o_ = 1.f / (1.f + __expf(-g3));
        float c_new = f_ * hc[m * 1024 + 512 + d] + i_ * gg;
        float h_new = o_ * tanhf(c_new);
        hc[m * 1024 + 512 + d] = c_new;
        short hb = f2bf(h_new);
        h16[m * 512 + d] = hb;
        allH[((size_t)t * 64 + m) * 512 + d] = hb;
    }
}

extern "C" void kernel_launch(void* const* d_in, const int* in_sizes, int n_in,
                              void* d_out, int out_size, void* d_ws, size_t ws_size,
                              hipStream_t stream)
{
    const float* enc        = (const float*)d_in[0];
    const int*   captions   = (const int*)d_in[1];
    const int*   lengths    = (const int*)d_in[2];
    const float* enc_att_w  = (const float*)d_in[3];
    const float* enc_att_b  = (const float*)d_in[4];
    const float* hid_att_w  = (const float*)d_in[5];
    const float* hid_att_b  = (const float*)d_in[6];
    const float* full_att_w = (const float*)d_in[7];
    const float* full_att_b = (const float*)d_in[8];
    const float* embw       = (const float*)d_in[9];
    const float* w_ih       = (const float*)d_in[10];
    const float* w_hh       = (const float*)d_in[11];
    const float* b_ih       = (const float*)d_in[12];
    const float* b_hh       = (const float*)d_in[13];
    const float* init_h_w   = (const float*)d_in[14];
    const float* init_h_b   = (const float*)d_in[15];
    const float* init_c_w   = (const float*)d_in[16];
    const float* init_c_b   = (const float*)d_in[17];
    const float* fbeta_w    = (const float*)d_in[18];
    const float* fbeta_b    = (const float*)d_in[19];
    const float* fc_w       = (const float*)d_in[20];
    const float* fc_b       = (const float*)d_in[21];

    float* out_pred  = (float*)d_out;                        // [64][19][10000]
    float* out_alpha = out_pred + (size_t)BB * TM1 * VV;     // [64][19][196]

    // ---- scratch in d_out pred region (46.4MB <= 48.64MB, dead before pred)
    char* pr = (char*)d_out;
    short* att1_16   = (short*)pr;  pr += 12845056;  // live in loop
    float* gates_emb = (float*)pr;  pr += 9961472;   // live (overlaid at init)
    short* wcat16    = (short*)pr;  pr += 4194304;   // live: [fbeta;whh] 4096x512
    short* wihe16    = (short*)pr;  pr += 8388608;   // live
    float* biascat   = (float*)pr;  pr += 16384;     // live (4096 f32)
    float* P3h       = (float*)pr;  pr += 1048576;   // live (64x4096 f32)
    float* alphaG    = (float*)pr;  pr += 50176;     // live (64x196 f32)
    short* hidattT   = (short*)pr;  pr += 524288;    // live (512x512)
    float* biasg     = (float*)pr;  pr += 8192;      // precompute only
    short* embA      = (short*)pr;  pr += 1245184;   // precompute only
    short* wihm16    = (short*)pr;  pr += 2097152;   // precompute only
    short* encw16    = (short*)pr;  pr += 2097152;   // dead after att1
    float* meanP     = (float*)pr;  pr += 3670016;   // dead after kReduceMean
    short* mean16    = (short*)pr;  pr += 262144;    // dead after init gemm

    // overlays (dead before their region's owner is written):
    short* initW16  = (short*)gates_emb;                      // 4.19MB
    float* biasInit = (float*)((char*)gates_emb + 4194304);   // 4KB
    float* hcP      = P3h;                                    // 1.0MB

    // ---- workspace
    char* wp = (char*)d_ws;
    float* hc    = (float*)wp;  wp += 262144;      // 64x1024 f32 (c in [:,512:])
    short* h16   = (short*)wp;  wp += 65536;       // 64x512 bf16
    short* x16   = (short*)wp;  wp += 262144;      // 64x2048 bf16
    short* allH  = (short*)wp;  wp += 1245184;     // 19x64x512 bf16
    short* fc16  = (short*)wp;  wp += 10240000;    // 10000x512 bf16
    wp += 131072;                                  // over-read pad (pred tiles)
    short* enc16 = (short*)wp;  wp += 51380224;    // 64x196x2048 bf16 (optional)
    const bool full = ((size_t)(wp - (char*)d_ws) <= ws_size);

    // ---- precompute ----
    kPrepW<<<7752, 256, 0, stream>>>(enc_att_w, hid_att_w, fbeta_w, w_hh, w_ih, fc_w,
                                     init_h_w, init_c_w,
                                     fbeta_b, b_ih, b_hh, init_h_b, init_c_b,
                                     encw16, wcat16, wihe16, wihm16, fc16, initW16,
                                     hidattT, biascat, biasg, biasInit);
    if (full) kMeanEnc<1><<<dim3(64, 8, 7), 256, 0, stream>>>(enc, enc16, meanP);
    else      kMeanEnc<0><<<dim3(64, 8, 7), 256, 0, stream>>>(enc, enc16, meanP);
    kEmbGather<<<304, 256, 0, stream>>>(embw, captions, embA);
    kReduceMean<<<64, 256, 0, stream>>>(meanP, mean16);

    // h0|c0 partials = mean16 @ initW16^T  (k-split x4) -> hcP; then reduce
    kGemm<3><<<dim3(16, 1, 4), 256, 0, stream>>>(mean16, CENC, initW16, CENC,
        nullptr, hcP, 1024, 8);
    kReduceHC<<<64, 256, 0, stream>>>(hcP, biasInit, hc, h16);

    // att1 = enc @ enc_att_w^T + b -> bf16 [12544][512]  (128-tile)
    if (full)
        kGemm128<0, 1, 1><<<392, 256, 0, stream>>>(enc16, CENC, encw16, CENC,
            enc_att_b, 512, 12544, nullptr, att1_16, 512, 32, nullptr);
    else
        kGemm128<1, 1, 1><<<392, 256, 0, stream>>>(enc, CENC, encw16, CENC,
            enc_att_b, 512, 12544, nullptr, att1_16, 512, 32, nullptr);

    // gates_emb = embA @ W_ih[:, :512]^T + (b_ih + b_hh)  (overwrites initW16)
    kGemm<0><<<dim3(32, 19, 1), 256, 0, stream>>>(embA, 512, wihm16, 512,
        biasg, gates_emb, 2048, 8);

    // ---- sequential decode: 3 kernels per step ----
    for (int t = 0; t < TM1; ++t) {
        kStepA<<<128, 256, 0, stream>>>(h16, wcat16, biascat, hidattT, hid_att_b,
            att1_16, full_att_w, full_att_b, lengths, P3h, alphaG, out_alpha, t);

        if (full) kStepC<1><<<512, 256, 0, stream>>>(alphaG, P3h, enc16, x16);
        else      kStepC<0><<<512, 256, 0, stream>>>(alphaG, P3h, enc, x16);

        kStepD<<<32, 256, 0, stream>>>(x16, wihe16, P3h, gates_emb, hc, h16, allH, t);
    }

    // ---- pred = allH @ fc_w^T + fc_b (masked, remapped; 128-tile) ----
    kGemm128<0, 2, 2><<<790, 256, 0, stream>>>(allH, 512, fc16, 512,
        fc_b, VV, TM1 * BB, out_pred, nullptr, VV, 8, lengths);
}

// Round 9
// 1322.809 us; speedup vs baseline: 1.4010x; 1.4010x over previous
//
#include <hip/hip_runtime.h>
#include <hip/hip_bf16.h>

typedef short short8  __attribute__((ext_vector_type(8)));
typedef float floatx4 __attribute__((ext_vector_type(4)));
typedef int   int4v   __attribute__((ext_vector_type(4)));

constexpr int BB = 64, PP = 196, CENC = 2048, HH = 512, AA = 512, EE = 512;
constexpr int VV = 10000, TT = 20, TM1 = 19;
constexpr int NCAT = 4608;  // 512 (att) + 2048 (fbeta) + 2048 (Whh)

__device__ __forceinline__ float bf2f(short u) {
    union { unsigned u; float f; } v; v.u = ((unsigned)(unsigned short)u) << 16; return v.f;
}
__device__ __forceinline__ short f2bf(float f) {
    union { float f; unsigned u; } v; v.f = f;
    unsigned r = v.u + 0x7FFF + ((v.u >> 16) & 1);
    return (short)(r >> 16);
}

// async global->LDS, 16B per lane; LDS dest = wave-uniform base + lane*16
#define GLL(gp, lp) __builtin_amdgcn_global_load_lds( \
    (const __attribute__((address_space(1))) void*)(gp), \
    (__attribute__((address_space(3))) void*)(lp), 16, 0, 0)

// ---------------------------------------------------------------------------
// Weight prep: f32 -> bf16 conversions + concatenations + bias builds.
// ---------------------------------------------------------------------------
__global__ __launch_bounds__(256)
void kPrepW(const float* __restrict__ encw_s, const float* __restrict__ haw,
            const float* __restrict__ fbw, const float* __restrict__ whh,
            const float* __restrict__ wih, const float* __restrict__ fcw,
            const float* __restrict__ ihw, const float* __restrict__ icw,
            const float* __restrict__ hab, const float* __restrict__ fbb,
            const float* __restrict__ bih, const float* __restrict__ bhh,
            const float* __restrict__ ihb, const float* __restrict__ icb,
            short* __restrict__ encw_d, short* __restrict__ wcat_d,
            short* __restrict__ wihe_d, short* __restrict__ wihm_d,
            short* __restrict__ fc_d, short* __restrict__ initW_d,
            float* __restrict__ biascat, float* __restrict__ biasg,
            float* __restrict__ biasInit)
{
    long e = ((long)blockIdx.x * 256 + threadIdx.x) * 8;
    const float* sp = nullptr; short* dp = nullptr; long de = 0;
    if (e < 1048576)       { sp = &encw_s[e]; dp = encw_d; de = e; }
    else if (e < 3407872)  { long u = e - 1048576; long row = u >> 9, col = u & 511;
                             sp = (row < 512) ? &haw[row * 512 + col]
                                : (row < 2560) ? &fbw[(row - 512) * 512 + col]
                                               : &whh[(row - 2560) * 512 + col];
                             dp = wcat_d; de = u; }
    else if (e < 7602176)  { long u = e - 3407872; long row = u >> 11, col = u & 2047;
                             sp = &wih[row * 2560 + 512 + col]; dp = wihe_d; de = u; }
    else if (e < 8650752)  { long u = e - 7602176; long row = u >> 9, col = u & 511;
                             sp = &wih[row * 2560 + col]; dp = wihm_d; de = u; }
    else if (e < 13770752) { long u = e - 8650752; sp = &fcw[u]; dp = fc_d; de = u; }
    else if (e < 15867904) { long u = e - 13770752;
                             sp = (u < 1048576) ? &ihw[u] : &icw[u - 1048576];
                             dp = initW_d; de = u; }
    else if (e < 15872512) { long u = e - 15867904;
                             for (int j = 0; j < 8; ++j) { long w = u + j;
                                 biascat[w] = (w < 512) ? hab[w] : ((w < 2560) ? fbb[w - 512] : 0.f); }
                             return; }
    else if (e < 15874560) { long u = e - 15872512;
                             for (int j = 0; j < 8; ++j) biasg[u + j] = bih[u + j] + bhh[u + j];
                             return; }
    else if (e < 15875584) { long u = e - 15874560;
                             for (int j = 0; j < 8; ++j) { long w = u + j;
                                 biasInit[w] = (w < 512) ? ihb[w] : icb[w - 512]; }
                             return; }
    else return;
    union { short s[8]; int4v v; } u8;
    #pragma unroll
    for (int j = 0; j < 8; ++j) u8.s[j] = f2bf(sp[j]);
    *reinterpret_cast<int4v*>(&dp[de]) = u8.v;
}

// p-split mean partials + enc f32->bf16. grid (64, 8, 7): 28 rows per z-block.
template<int FULL>
__global__ __launch_bounds__(256)
void kMeanEnc(const float* __restrict__ enc, short* __restrict__ enc16,
              float* __restrict__ meanP)
{
    int b = blockIdx.x, kc = blockIdx.y, pz = blockIdx.z;
    int k = kc * 256 + threadIdx.x;
    const float* eb = &enc[((size_t)b * PP + pz * 28) * CENC + k];
    short* ob = &enc16[((size_t)b * PP + pz * 28) * CENC + k];
    float s0 = 0, s1 = 0, s2 = 0, s3 = 0;
    for (int p = 0; p < 28; p += 4) {
        float v0 = eb[(size_t)(p + 0) * CENC], v1 = eb[(size_t)(p + 1) * CENC];
        float v2 = eb[(size_t)(p + 2) * CENC], v3 = eb[(size_t)(p + 3) * CENC];
        s0 += v0; s1 += v1; s2 += v2; s3 += v3;
        if (FULL) {
            ob[(size_t)(p + 0) * CENC] = f2bf(v0); ob[(size_t)(p + 1) * CENC] = f2bf(v1);
            ob[(size_t)(p + 2) * CENC] = f2bf(v2); ob[(size_t)(p + 3) * CENC] = f2bf(v3);
        }
    }
    meanP[((size_t)pz * 64 + b) * 2048 + k] = (s0 + s1) + (s2 + s3);
}

// reduce 7 meanP partials -> mean16 bf16 [64][2048]
__global__ __launch_bounds__(256)
void kReduceMean(const float* __restrict__ meanP, short* __restrict__ mean16)
{
    int b = blockIdx.x, c0 = threadIdx.x * 8;
    const float inv = 1.0f / PP;
    union { short s[8]; int4v v; } u8;
    #pragma unroll
    for (int j = 0; j < 8; ++j) {
        float s = 0.f;
        #pragma unroll
        for (int pz = 0; pz < 7; ++pz) s += meanP[((size_t)pz * 64 + b) * 2048 + c0 + j];
        u8.s[j] = f2bf(s * inv);
    }
    *reinterpret_cast<int4v*>(&mean16[b * 2048 + c0]) = u8.v;
}

// embedding gather -> embA[r = t*64+b][512] bf16
__global__ __launch_bounds__(256)
void kEmbGather(const float* __restrict__ embw, const int* __restrict__ captions,
                short* __restrict__ embA)
{
    long e = ((long)blockIdx.x * 256 + threadIdx.x) * 8;
    int r = (int)(e >> 9), j = (int)(e & 511);
    int t = r >> 6, b = r & 63;
    int tok = captions[b * TT + t];
    const float* sp = &embw[(size_t)tok * EE + j];
    union { short s[8]; int4v v; } u8;
    #pragma unroll
    for (int q = 0; q < 8; ++q) u8.s[q] = f2bf(sp[q]);
    *reinterpret_cast<int4v*>(&embA[e]) = u8.v;
}

// ---------------------------------------------------------------------------
// MFMA bf16 GEMM: C[M,N] = A[M,K] @ W[N,K]^T. Tile 64x64, BK=64, 4 waves.
// AOP: 0 = A bf16 (gll); 1 = A f32 (register convert staging)
// WOP: 0 = plain row n0+r (bounds vs Ntot); 1 = gate-interleaved LSTM rows
// EOP: 0 = f32 +bias; 1 = bf16 +bias; 2 = pred (mask/remap);
//      3 = plain k-partials; 4 = gate-layout k-partials
// SWZ: 0 = (x,y,z)=(nb,mb,kz); 1 = att1 XCD swizzle; 2 = pred swizzle
// ---------------------------------------------------------------------------
template<int AOP, int WOP, int EOP, int SWZ>
__global__ __launch_bounds__(256)
void kGemm(const void* __restrict__ Ap, int lda, const short* __restrict__ W, int ldw,
           const float* __restrict__ bias, int Ntot,
           float* __restrict__ outF, int ldc, short* __restrict__ outB,
           int nk, const int* __restrict__ lengths)
{
    __shared__ short As[64 * 64];
    __shared__ short Ws[64 * 64];
    int nb, mb, kz;
    if (SWZ == 0) { nb = blockIdx.x; mb = blockIdx.y; kz = blockIdx.z; }
    else if (SWZ == 1) {  // att1: 1568 blocks, group 8 same-A n-blocks per XCD
        int j = blockIdx.x;
        if (j < 1536) { mb = (j >> 6) * 8 + (j & 7); nb = (j >> 3) & 7; }
        else          { int u = j - 1536; mb = 192 + (u >> 3); nb = u & 7; }
        kz = 0;
    } else {              // pred: 3040 blocks
        int j = blockIdx.x; int c = j & 7, s = j >> 3;
        mb = s % 19; int u = s / 19; nb = 8 * u + c; kz = 0;
        if (nb * 64 >= Ntot) return;
    }
    const int tid = threadIdx.x;
    const int m0 = mb * 64, n0 = nb * 64, k0 = kz * nk * 64;
    const int w = tid >> 6, l = tid & 63;
    floatx4 acc[4] = {};

    for (int ks = 0; ks < nk; ++ks) {
        int kt = k0 + ks * 64;
        // ---- stage A ----
        if (AOP == 0) {
            const short* A = (const short*)Ap;
            #pragma unroll
            for (int i = 0; i < 2; ++i) {
                int ii = w * 2 + i;                 // 8 x 1KB slots
                int row = ii * 8 + (l >> 3);
                int cg = l & 7;
                const short* gp = &A[(size_t)(m0 + row) * lda + kt + ((cg ^ (row & 7)) << 3)];
                GLL(gp, &As[ii * 512]);
            }
        } else {
            const float* A = (const float*)Ap;
            #pragma unroll
            for (int i = 0; i < 2; ++i) {
                int s = tid + i * 256, row = s >> 3, cg = s & 7;
                const float* sp = &A[(size_t)(m0 + row) * lda + kt + cg * 8];
                float4 a = *reinterpret_cast<const float4*>(sp);
                float4 b = *reinterpret_cast<const float4*>(sp + 4);
                union { short s[8]; int4v v; } u8;
                u8.s[0]=f2bf(a.x); u8.s[1]=f2bf(a.y); u8.s[2]=f2bf(a.z); u8.s[3]=f2bf(a.w);
                u8.s[4]=f2bf(b.x); u8.s[5]=f2bf(b.y); u8.s[6]=f2bf(b.z); u8.s[7]=f2bf(b.w);
                *reinterpret_cast<int4v*>(&As[row * 64 + ((cg ^ (row & 7)) << 3)]) = u8.v;
            }
        }
        // ---- stage W (gll) ----
        #pragma unroll
        for (int i = 0; i < 2; ++i) {
            int ii = w * 2 + i;
            int r = ii * 8 + (l >> 3);
            int cg = l & 7;
            int wr;
            if (WOP == 1) wr = 512 * (r >> 4) + 16 * nb + (r & 15);
            else          wr = n0 + r;
            if (WOP == 1 || wr < Ntot) {
                const short* gp = &W[(size_t)wr * ldw + kt + ((cg ^ (r & 7)) << 3)];
                GLL(gp, &Ws[ii * 512]);
            }
        }
        __syncthreads();
        // ---- MFMA ----
        #pragma unroll
        for (int kc = 0; kc < 2; ++kc) {
            int arow = 16 * w + (l & 15);
            int cg = 4 * kc + (l >> 4);
            short8 af = *reinterpret_cast<const short8*>(&As[arow * 64 + ((cg ^ (arow & 7)) << 3)]);
            #pragma unroll
            for (int q = 0; q < 4; ++q) {
                int wrow = 16 * q + (l & 15);
                short8 wf = *reinterpret_cast<const short8*>(&Ws[wrow * 64 + ((cg ^ (wrow & 7)) << 3)]);
                acc[q] = __builtin_amdgcn_mfma_f32_16x16x32_bf16(af, wf, acc[q], 0, 0, 0);
            }
        }
        __syncthreads();
    }
    // ---- epilogue ----
    int l4 = l >> 4, l15 = l & 15;
    #pragma unroll
    for (int q = 0; q < 4; ++q) {
        #pragma unroll
        for (int j = 0; j < 4; ++j) {
            int m = m0 + 16 * w + 4 * l4 + j;
            int n = n0 + 16 * q + l15;
            float val = acc[q][j];
            if (EOP == 0) {
                outF[(size_t)m * ldc + n] = val + bias[n];
            } else if (EOP == 1) {
                outB[(size_t)m * ldc + n] = f2bf(val + bias[n]);
            } else if (EOP == 2) {
                if (n < Ntot) {
                    int b = m & 63, tt = m >> 6;
                    bool act = tt < (lengths[b] - 1);
                    outF[((size_t)b * TM1 + tt) * VV + n] = act ? (val + bias[n]) : 0.f;
                }
            } else if (EOP == 3) {  // plain k-partials
                int mloc = m - m0;
                outF[((size_t)kz * 64 + mloc) * ldc + n] = val;
            } else {                // EOP == 4: gate-layout k-partials
                int col = 512 * q + (n0 >> 2) + l15;
                int mloc = m - m0;
                outF[((size_t)kz * 64 + mloc) * 2048 + col] = val;
            }
        }
    }
}

__global__ __launch_bounds__(256)
void kReduceHC(const float* __restrict__ Pc, const float* __restrict__ biasInit,
               float* __restrict__ hc, short* __restrict__ h16)
{
    int b = blockIdx.x, tid = threadIdx.x;
    for (int j = tid; j < 1024; j += 256) {
        float s = Pc[((size_t)0 * BB + b) * 1024 + j] + Pc[((size_t)1 * BB + b) * 1024 + j]
                + Pc[((size_t)2 * BB + b) * 1024 + j] + Pc[((size_t)3 * BB + b) * 1024 + j];
        s += biasInit[j];
        hc[b * 1024 + j] = s;
        if (j < 512) h16[b * 512 + j] = f2bf(s);
    }
}

// ---------------------------------------------------------------------------
// Fused Step B+C (256 blocks: b = blk&63, kc = blk>>6 in 0..3):
//   block recomputes alpha for its b (att1 read 4x redundant across kc),
//   then its 512-col awe slice (two 256-col passes) + gate -> x16.
//   out_alpha written by kc==0 blocks only. alpha lives in LDS only.
// ---------------------------------------------------------------------------
template<int FULL>
__global__ __launch_bounds__(256)
void kStepBC(const short* __restrict__ att1, const float* __restrict__ P3h,
             const float* __restrict__ faw, const float* __restrict__ fab,
             const int* __restrict__ lengths, const void* __restrict__ encp,
             short* __restrict__ x16, float* __restrict__ alpha_out, int t)
{
    int blk = blockIdx.x, tid = threadIdx.x;
    int b = blk & 63, kc = blk >> 6;
    __shared__ float att2s[512];
    __shared__ float fw[512];
    __shared__ float es[PP];
    __shared__ float alps[PP];
    __shared__ float red[8];
    __shared__ float part[8][256];

    for (int a = tid; a < 512; a += 256) { att2s[a] = P3h[b * NCAT + a]; fw[a] = faw[a]; }
    __syncthreads();

    int wv = tid >> 6, lane = tid & 63;
    // e[p] = relu(att1[p]+att2).faw + fab
    for (int p = wv; p < PP; p += 4) {
        short8 v = *reinterpret_cast<const short8*>(&att1[((size_t)b * PP + p) * 512 + lane * 8]);
        float s = 0.f;
        #pragma unroll
        for (int j = 0; j < 8; ++j) {
            float x = bf2f(v[j]) + att2s[lane * 8 + j];
            s += fmaxf(x, 0.f) * fw[lane * 8 + j];
        }
        #pragma unroll
        for (int off = 32; off > 0; off >>= 1) s += __shfl_down(s, off, 64);
        if (lane == 0) es[p] = s + fab[0];
    }
    __syncthreads();
    // softmax over 196
    float m = -1e30f;
    for (int p = tid; p < PP; p += 256) m = fmaxf(m, es[p]);
    #pragma unroll
    for (int off = 32; off > 0; off >>= 1) m = fmaxf(m, __shfl_down(m, off, 64));
    if (lane == 0) red[wv] = m;
    __syncthreads();
    m = fmaxf(fmaxf(red[0], red[1]), fmaxf(red[2], red[3]));
    float ssum = 0.f;
    for (int p = tid; p < PP; p += 256) { float ev = __expf(es[p] - m); es[p] = ev; ssum += ev; }
    #pragma unroll
    for (int off = 32; off > 0; off >>= 1) ssum += __shfl_down(ssum, off, 64);
    if (lane == 0) red[4 + wv] = ssum;
    __syncthreads();
    float inv = 1.f / (red[4] + red[5] + red[6] + red[7]);
    bool active = t < (lengths[b] - 1);
    for (int p = tid; p < PP; p += 256) {
        float al = es[p] * inv;
        alps[p] = al;
        if (kc == 0)
            alpha_out[((size_t)b * TM1 + t) * PP + p] = active ? al : 0.f;
    }
    __syncthreads();

    // awe for 512-col slice, two 256-col passes
    #pragma unroll
    for (int half = 0; half < 2; ++half) {
        int base = kc * 512 + half * 256;
        if (FULL) {
            const short* enc16 = (const short*)encp;
            int g = tid & 31, prow = tid >> 5;      // 8 cols/thread, 8 p-lanes
            int k0 = base + g * 8;
            float acc[8] = {};
            for (int p = prow; p < PP; p += 8) {
                short8 v = *reinterpret_cast<const short8*>(&enc16[((size_t)b * PP + p) * CENC + k0]);
                float a_ = alps[p];
                #pragma unroll
                for (int j = 0; j < 8; ++j) acc[j] = fmaf(bf2f(v[j]), a_, acc[j]);
            }
            *reinterpret_cast<float4*>(&part[prow][g * 8])     = make_float4(acc[0], acc[1], acc[2], acc[3]);
            *reinterpret_cast<float4*>(&part[prow][g * 8 + 4]) = make_float4(acc[4], acc[5], acc[6], acc[7]);
            __syncthreads();
            int c = tid;
            float awe = 0.f;
            #pragma unroll
            for (int pr = 0; pr < 8; ++pr) awe += part[pr][c];
            int k = base + c;
            float gate = 1.f / (1.f + __expf(-P3h[b * NCAT + 512 + k]));
            x16[(size_t)b * CENC + k] = f2bf(gate * awe);
            __syncthreads();
        } else {
            const float* enc = (const float*)encp;
            int g = tid & 63, prow = tid >> 6;      // 4 cols/thread, 4 p-lanes
            int k0 = base + g * 4;
            float acc[4] = {};
            for (int p = prow; p < PP; p += 4) {
                float4 v = *reinterpret_cast<const float4*>(&enc[((size_t)b * PP + p) * CENC + k0]);
                float a_ = alps[p];
                acc[0] = fmaf(v.x, a_, acc[0]); acc[1] = fmaf(v.y, a_, acc[1]);
                acc[2] = fmaf(v.z, a_, acc[2]); acc[3] = fmaf(v.w, a_, acc[3]);
            }
            *reinterpret_cast<float4*>(&part[prow][g * 4]) = make_float4(acc[0], acc[1], acc[2], acc[3]);
            __syncthreads();
            int c = tid;
            float awe = part[0][c] + part[1][c] + part[2][c] + part[3][c];
            int k = base + c;
            float gate = 1.f / (1.f + __expf(-P3h[b * NCAT + 512 + k]));
            x16[(size_t)b * CENC + k] = f2bf(gate * awe);
            __syncthreads();
        }
    }
}

// ---------------------------------------------------------------------------
// Step D2 (128 blocks: b = blk&63, d-half = blk>>6): reduce 8 gate partials
// + emb part + Whh part; LSTM cell update. One d per thread.
// ---------------------------------------------------------------------------
__global__ __launch_bounds__(256)
void kStepD2(const float* __restrict__ Pg, const float* __restrict__ gates_emb,
             const float* __restrict__ P3h, float* __restrict__ hc,
             short* __restrict__ h16, short* __restrict__ allH, int t)
{
    int blk = blockIdx.x, tid = threadIdx.x;
    int b = blk & 63;
    int d = (blk >> 6) * 256 + tid;
    float g4[4];
    #pragma unroll
    for (int q = 0; q < 4; ++q) {
        int col = q * 512 + d;
        float s = gates_emb[((size_t)t * 64 + b) * 2048 + col] + P3h[b * NCAT + 2560 + col];
        #pragma unroll
        for (int kz = 0; kz < 8; ++kz) s += Pg[((size_t)kz * 64 + b) * 2048 + col];
        g4[q] = s;
    }
    float i_ = 1.f / (1.f + __expf(-g4[0]));
    float f_ = 1.f / (1.f + __expf(-g4[1]));
    float g_ = tanhf(g4[2]);
    float o_ = 1.f / (1.f + __expf(-g4[3]));
    float c_new = f_ * hc[b * 1024 + 512 + d] + i_ * g_;
    float h_new = o_ * tanhf(c_new);
    hc[b * 1024 + 512 + d] = c_new;
    short hb = f2bf(h_new);
    h16[b * 512 + d] = hb;
    allH[((size_t)t * 64 + b) * 512 + d] = hb;
}

extern "C" void kernel_launch(void* const* d_in, const int* in_sizes, int n_in,
                              void* d_out, int out_size, void* d_ws, size_t ws_size,
                              hipStream_t stream)
{
    const float* enc        = (const float*)d_in[0];
    const int*   captions   = (const int*)d_in[1];
    const int*   lengths    = (const int*)d_in[2];
    const float* enc_att_w  = (const float*)d_in[3];
    const float* enc_att_b  = (const float*)d_in[4];
    const float* hid_att_w  = (const float*)d_in[5];
    const float* hid_att_b  = (const float*)d_in[6];
    const float* full_att_w = (const float*)d_in[7];
    const float* full_att_b = (const float*)d_in[8];
    const float* embw       = (const float*)d_in[9];
    const float* w_ih       = (const float*)d_in[10];
    const float* w_hh       = (const float*)d_in[11];
    const float* b_ih       = (const float*)d_in[12];
    const float* b_hh       = (const float*)d_in[13];
    const float* init_h_w   = (const float*)d_in[14];
    const float* init_h_b   = (const float*)d_in[15];
    const float* init_c_w   = (const float*)d_in[16];
    const float* init_c_b   = (const float*)d_in[17];
    const float* fbeta_w    = (const float*)d_in[18];
    const float* fbeta_b    = (const float*)d_in[19];
    const float* fc_w       = (const float*)d_in[20];
    const float* fc_b       = (const float*)d_in[21];

    float* out_pred  = (float*)d_out;                        // [64][19][10000]
    float* out_alpha = out_pred + (size_t)BB * TM1 * VV;     // [64][19][196]

    // ---- scratch in d_out pred region (dead before pred GEMM)
    char* pr = (char*)d_out;
    short* att1_16   = (short*)pr;  pr += 12845056;  // live in loop
    float* gates_emb = (float*)pr;  pr += 9961472;   // live (overlaid at init)
    short* wcat16    = (short*)pr;  pr += 4718592;   // live [hid_att;fbeta;whh]
    short* wihe16    = (short*)pr;  pr += 8388608;   // live
    float* biascat   = (float*)pr;  pr += 18432;     // live (4608 f32)
    float* P3h       = (float*)pr;  pr += 1179648;   // live (64x4608 f32)
    short* embA      = (short*)pr;  pr += 1245184;   // precompute only
    short* wihm16    = (short*)pr;  pr += 2097152;   // precompute only
    short* encw16    = (short*)pr;  pr += 2097152;   // dead after att1
    float* biasg     = (float*)pr;  pr += 8192;      // precompute only
    float* meanP     = (float*)pr;  pr += 3670016;   // dead after kReduceMean
    short* mean16    = (short*)pr;  pr += 262144;    // dead after init gemm

    // overlays (dead before their region's owner is written):
    short* initW16  = (short*)gates_emb;                      // 4.19MB
    float* biasInit = (float*)((char*)gates_emb + 4194304);   // 4KB
    float* hcP      = P3h;                                    // 1.0MB

    // ---- workspace
    char* wp = (char*)d_ws;
    float* hc    = (float*)wp;  wp += 262144;      // 64x1024 f32 (c in [:,512:])
    short* h16   = (short*)wp;  wp += 65536;       // 64x512 bf16
    short* x16   = (short*)wp;  wp += 262144;      // 64x2048 bf16
    float* Pg    = (float*)wp;  wp += 4194304;     // 8x64x2048 f32 gate partials
    short* fc16  = (short*)wp;  wp += 10240000;    // 10000x512 bf16
    short* allH  = (short*)wp;  wp += 1245184;     // 19x64x512 bf16
    short* enc16 = (short*)wp;  wp += 51380224;    // 64x196x2048 bf16 (optional)
    const bool full = ((size_t)(wp - (char*)d_ws) <= ws_size);

    // ---- precompute ----
    kPrepW<<<7752, 256, 0, stream>>>(enc_att_w, hid_att_w, fbeta_w, w_hh, w_ih, fc_w,
                                     init_h_w, init_c_w,
                                     hid_att_b, fbeta_b, b_ih, b_hh, init_h_b, init_c_b,
                                     encw16, wcat16, wihe16, wihm16, fc16, initW16,
                                     biascat, biasg, biasInit);
    if (full) kMeanEnc<1><<<dim3(64, 8, 7), 256, 0, stream>>>(enc, enc16, meanP);
    else      kMeanEnc<0><<<dim3(64, 8, 7), 256, 0, stream>>>(enc, enc16, meanP);
    kEmbGather<<<304, 256, 0, stream>>>(embw, captions, embA);
    kReduceMean<<<64, 256, 0, stream>>>(meanP, mean16);

    // h0|c0 partials = mean16 @ initW16^T  (MFMA, k-split x4) -> hcP
    kGemm<0, 0, 3, 0><<<dim3(16, 1, 4), 256, 0, stream>>>(mean16, CENC, initW16, CENC,
        nullptr, 1024, hcP, 1024, nullptr, 8, nullptr);
    kReduceHC<<<64, 256, 0, stream>>>(hcP, biasInit, hc, h16);

    // att1 = enc @ enc_att_w^T + b -> bf16 [12544][512]
    if (full)
        kGemm<0, 0, 1, 1><<<1568, 256, 0, stream>>>(enc16, CENC, encw16, CENC,
            enc_att_b, 512, nullptr, 512, att1_16, 32, nullptr);
    else
        kGemm<1, 0, 1, 1><<<1568, 256, 0, stream>>>(enc, CENC, encw16, CENC,
            enc_att_b, 512, nullptr, 512, att1_16, 32, nullptr);

    // gates_emb = embA @ W_ih[:, :512]^T + (b_ih + b_hh)  (overwrites initW16)
    kGemm<0, 0, 0, 0><<<dim3(32, 19, 1), 256, 0, stream>>>(embA, 512, wihm16, 512,
        biasg, 2048, gates_emb, 2048, nullptr, 8, nullptr);

    // ---- sequential decode: 4 kernels per step ----
    for (int t = 0; t < TM1; ++t) {
        // P3h = h @ [hid_att_w ; fbeta_w ; W_hh]^T + biascat  -> [64][4608]
        kGemm<0, 0, 0, 0><<<dim3(72, 1, 1), 256, 0, stream>>>(h16, 512, wcat16, 512,
            biascat, NCAT, P3h, NCAT, nullptr, 8, nullptr);

        if (full) kStepBC<1><<<256, 256, 0, stream>>>(att1_16, P3h, full_att_w,
            full_att_b, lengths, enc16, x16, out_alpha, t);
        else      kStepBC<0><<<256, 256, 0, stream>>>(att1_16, P3h, full_att_w,
            full_att_b, lengths, enc, x16, out_alpha, t);

        // gate partials: x @ W_ih[:, 512:]^T (gate-interleaved rows), k-split x8
        kGemm<0, 1, 4, 0><<<dim3(32, 1, 8), 256, 0, stream>>>(x16, CENC, wihe16, CENC,
            nullptr, 2048, Pg, 2048, nullptr, 4, nullptr);

        kStepD2<<<128, 256, 0, stream>>>(Pg, gates_emb, P3h, hc, h16, allH, t);
    }

    // ---- pred = allH @ fc_w^T + fc_b (masked, remapped) ----
    kGemm<0, 0, 2, 2><<<3040, 256, 0, stream>>>(allH, 512, fc16, 512,
        fc_b, VV, out_pred, VV, nullptr, 8, lengths);
}

// Round 10
// 1227.180 us; speedup vs baseline: 1.5102x; 1.0779x over previous
//
#include <hip/hip_runtime.h>
#include <hip/hip_bf16.h>

typedef short short8  __attribute__((ext_vector_type(8)));
typedef float floatx4 __attribute__((ext_vector_type(4)));
typedef int   int4v   __attribute__((ext_vector_type(4)));

constexpr int BB = 64, PP = 196, CENC = 2048, HH = 512, AA = 512, EE = 512;
constexpr int VV = 10000, TT = 20, TM1 = 19;
constexpr int NCAT = 4608;  // 512 (att) + 2048 (fbeta) + 2048 (Whh)

__device__ __forceinline__ float bf2f(short u) {
    union { unsigned u; float f; } v; v.u = ((unsigned)(unsigned short)u) << 16; return v.f;
}
__device__ __forceinline__ short f2bf(float f) {
    union { float f; unsigned u; } v; v.f = f;
    unsigned r = v.u + 0x7FFF + ((v.u >> 16) & 1);
    return (short)(r >> 16);
}

// async global->LDS, 16B per lane; LDS dest = wave-uniform base + lane*16
#define GLL(gp, lp) __builtin_amdgcn_global_load_lds( \
    (const __attribute__((address_space(1))) void*)(gp), \
    (__attribute__((address_space(3))) void*)(lp), 16, 0, 0)

// ---------------------------------------------------------------------------
// Weight prep: f32 -> bf16 conversions + concatenations + bias builds.
// ---------------------------------------------------------------------------
__global__ __launch_bounds__(256)
void kPrepW(const float* __restrict__ encw_s, const float* __restrict__ haw,
            const float* __restrict__ fbw, const float* __restrict__ whh,
            const float* __restrict__ wih, const float* __restrict__ fcw,
            const float* __restrict__ ihw, const float* __restrict__ icw,
            const float* __restrict__ hab, const float* __restrict__ fbb,
            const float* __restrict__ bih, const float* __restrict__ bhh,
            const float* __restrict__ ihb, const float* __restrict__ icb,
            short* __restrict__ encw_d, short* __restrict__ wcat_d,
            short* __restrict__ wihe_d, short* __restrict__ wihm_d,
            short* __restrict__ fc_d, short* __restrict__ initW_d,
            float* __restrict__ biascat, float* __restrict__ biasg,
            float* __restrict__ biasInit)
{
    long e = ((long)blockIdx.x * 256 + threadIdx.x) * 8;
    const float* sp = nullptr; short* dp = nullptr; long de = 0;
    if (e < 1048576)       { sp = &encw_s[e]; dp = encw_d; de = e; }
    else if (e < 3407872)  { long u = e - 1048576; long row = u >> 9, col = u & 511;
                             sp = (row < 512) ? &haw[row * 512 + col]
                                : (row < 2560) ? &fbw[(row - 512) * 512 + col]
                                               : &whh[(row - 2560) * 512 + col];
                             dp = wcat_d; de = u; }
    else if (e < 7602176)  { long u = e - 3407872; long row = u >> 11, col = u & 2047;
                             sp = &wih[row * 2560 + 512 + col]; dp = wihe_d; de = u; }
    else if (e < 8650752)  { long u = e - 7602176; long row = u >> 9, col = u & 511;
                             sp = &wih[row * 2560 + col]; dp = wihm_d; de = u; }
    else if (e < 13770752) { long u = e - 8650752; sp = &fcw[u]; dp = fc_d; de = u; }
    else if (e < 15867904) { long u = e - 13770752;
                             sp = (u < 1048576) ? &ihw[u] : &icw[u - 1048576];
                             dp = initW_d; de = u; }
    else if (e < 15872512) { long u = e - 15867904;
                             for (int j = 0; j < 8; ++j) { long w = u + j;
                                 biascat[w] = (w < 512) ? hab[w] : ((w < 2560) ? fbb[w - 512] : 0.f); }
                             return; }
    else if (e < 15874560) { long u = e - 15872512;
                             for (int j = 0; j < 8; ++j) biasg[u + j] = bih[u + j] + bhh[u + j];
                             return; }
    else if (e < 15875584) { long u = e - 15874560;
                             for (int j = 0; j < 8; ++j) { long w = u + j;
                                 biasInit[w] = (w < 512) ? ihb[w] : icb[w - 512]; }
                             return; }
    else return;
    union { short s[8]; int4v v; } u8;
    #pragma unroll
    for (int j = 0; j < 8; ++j) u8.s[j] = f2bf(sp[j]);
    *reinterpret_cast<int4v*>(&dp[de]) = u8.v;
}

// p-split mean partials + enc f32->bf16. grid (64, 8, 7): 28 rows per z-block.
template<int FULL>
__global__ __launch_bounds__(256)
void kMeanEnc(const float* __restrict__ enc, short* __restrict__ enc16,
              float* __restrict__ meanP)
{
    int b = blockIdx.x, kc = blockIdx.y, pz = blockIdx.z;
    int k = kc * 256 + threadIdx.x;
    const float* eb = &enc[((size_t)b * PP + pz * 28) * CENC + k];
    short* ob = &enc16[((size_t)b * PP + pz * 28) * CENC + k];
    float s0 = 0, s1 = 0, s2 = 0, s3 = 0;
    for (int p = 0; p < 28; p += 4) {
        float v0 = eb[(size_t)(p + 0) * CENC], v1 = eb[(size_t)(p + 1) * CENC];
        float v2 = eb[(size_t)(p + 2) * CENC], v3 = eb[(size_t)(p + 3) * CENC];
        s0 += v0; s1 += v1; s2 += v2; s3 += v3;
        if (FULL) {
            ob[(size_t)(p + 0) * CENC] = f2bf(v0); ob[(size_t)(p + 1) * CENC] = f2bf(v1);
            ob[(size_t)(p + 2) * CENC] = f2bf(v2); ob[(size_t)(p + 3) * CENC] = f2bf(v3);
        }
    }
    meanP[((size_t)pz * 64 + b) * 2048 + k] = (s0 + s1) + (s2 + s3);
}

// reduce 7 meanP partials -> mean16 bf16 [64][2048]
__global__ __launch_bounds__(256)
void kReduceMean(const float* __restrict__ meanP, short* __restrict__ mean16)
{
    int b = blockIdx.x, c0 = threadIdx.x * 8;
    const float inv = 1.0f / PP;
    union { short s[8]; int4v v; } u8;
    #pragma unroll
    for (int j = 0; j < 8; ++j) {
        float s = 0.f;
        #pragma unroll
        for (int pz = 0; pz < 7; ++pz) s += meanP[((size_t)pz * 64 + b) * 2048 + c0 + j];
        u8.s[j] = f2bf(s * inv);
    }
    *reinterpret_cast<int4v*>(&mean16[b * 2048 + c0]) = u8.v;
}

// embedding gather -> embA[r = t*64+b][512] bf16
__global__ __launch_bounds__(256)
void kEmbGather(const float* __restrict__ embw, const int* __restrict__ captions,
                short* __restrict__ embA)
{
    long e = ((long)blockIdx.x * 256 + threadIdx.x) * 8;
    int r = (int)(e >> 9), j = (int)(e & 511);
    int t = r >> 6, b = r & 63;
    int tok = captions[b * TT + t];
    const float* sp = &embw[(size_t)tok * EE + j];
    union { short s[8]; int4v v; } u8;
    #pragma unroll
    for (int q = 0; q < 8; ++q) u8.s[q] = f2bf(sp[q]);
    *reinterpret_cast<int4v*>(&embA[e]) = u8.v;
}

// ---------------------------------------------------------------------------
// MFMA bf16 GEMM: C[M,N] = A[M,K] @ W[N,K]^T. Tile 64x64, BK=64, 4 waves.
// AOP: 0 = A bf16 (gll); 1 = A f32 (register convert staging)
// WOP: 0 = plain row n0+r (bounds vs Ntot); 1 = gate-interleaved LSTM rows
// EOP: 0 = f32 +bias; 1 = bf16 +bias; 2 = pred (mask/remap);
//      3 = plain k-partials; 4 = gate-layout k-partials
// SWZ: 0 = (x,y,z)=(nb,mb,kz); 1 = att1 XCD swizzle; 2 = pred swizzle
// ---------------------------------------------------------------------------
template<int AOP, int WOP, int EOP, int SWZ>
__global__ __launch_bounds__(256)
void kGemm(const void* __restrict__ Ap, int lda, const short* __restrict__ W, int ldw,
           const float* __restrict__ bias, int Ntot,
           float* __restrict__ outF, int ldc, short* __restrict__ outB,
           int nk, const int* __restrict__ lengths)
{
    __shared__ short As[64 * 64];
    __shared__ short Ws[64 * 64];
    int nb, mb, kz;
    if (SWZ == 0) { nb = blockIdx.x; mb = blockIdx.y; kz = blockIdx.z; }
    else if (SWZ == 1) {  // att1: 1568 blocks, group 8 same-A n-blocks per XCD
        int j = blockIdx.x;
        if (j < 1536) { mb = (j >> 6) * 8 + (j & 7); nb = (j >> 3) & 7; }
        else          { int u = j - 1536; mb = 192 + (u >> 3); nb = u & 7; }
        kz = 0;
    } else {              // pred: 3040 blocks
        int j = blockIdx.x; int c = j & 7, s = j >> 3;
        mb = s % 19; int u = s / 19; nb = 8 * u + c; kz = 0;
        if (nb * 64 >= Ntot) return;
    }
    const int tid = threadIdx.x;
    const int m0 = mb * 64, n0 = nb * 64, k0 = kz * nk * 64;
    const int w = tid >> 6, l = tid & 63;
    floatx4 acc[4] = {};

    for (int ks = 0; ks < nk; ++ks) {
        int kt = k0 + ks * 64;
        // ---- stage A ----
        if (AOP == 0) {
            const short* A = (const short*)Ap;
            #pragma unroll
            for (int i = 0; i < 2; ++i) {
                int ii = w * 2 + i;                 // 8 x 1KB slots
                int row = ii * 8 + (l >> 3);
                int cg = l & 7;
                const short* gp = &A[(size_t)(m0 + row) * lda + kt + ((cg ^ (row & 7)) << 3)];
                GLL(gp, &As[ii * 512]);
            }
        } else {
            const float* A = (const float*)Ap;
            #pragma unroll
            for (int i = 0; i < 2; ++i) {
                int s = tid + i * 256, row = s >> 3, cg = s & 7;
                const float* sp = &A[(size_t)(m0 + row) * lda + kt + cg * 8];
                float4 a = *reinterpret_cast<const float4*>(sp);
                float4 b = *reinterpret_cast<const float4*>(sp + 4);
                union { short s[8]; int4v v; } u8;
                u8.s[0]=f2bf(a.x); u8.s[1]=f2bf(a.y); u8.s[2]=f2bf(a.z); u8.s[3]=f2bf(a.w);
                u8.s[4]=f2bf(b.x); u8.s[5]=f2bf(b.y); u8.s[6]=f2bf(b.z); u8.s[7]=f2bf(b.w);
                *reinterpret_cast<int4v*>(&As[row * 64 + ((cg ^ (row & 7)) << 3)]) = u8.v;
            }
        }
        // ---- stage W (gll) ----
        #pragma unroll
        for (int i = 0; i < 2; ++i) {
            int ii = w * 2 + i;
            int r = ii * 8 + (l >> 3);
            int cg = l & 7;
            int wr;
            if (WOP == 1) wr = 512 * (r >> 4) + 16 * nb + (r & 15);
            else          wr = n0 + r;
            if (WOP == 1 || wr < Ntot) {
                const short* gp = &W[(size_t)wr * ldw + kt + ((cg ^ (r & 7)) << 3)];
                GLL(gp, &Ws[ii * 512]);
            }
        }
        __syncthreads();
        // ---- MFMA ----
        #pragma unroll
        for (int kc = 0; kc < 2; ++kc) {
            int arow = 16 * w + (l & 15);
            int cg = 4 * kc + (l >> 4);
            short8 af = *reinterpret_cast<const short8*>(&As[arow * 64 + ((cg ^ (arow & 7)) << 3)]);
            #pragma unroll
            for (int q = 0; q < 4; ++q) {
                int wrow = 16 * q + (l & 15);
                short8 wf = *reinterpret_cast<const short8*>(&Ws[wrow * 64 + ((cg ^ (wrow & 7)) << 3)]);
                acc[q] = __builtin_amdgcn_mfma_f32_16x16x32_bf16(af, wf, acc[q], 0, 0, 0);
            }
        }
        __syncthreads();
    }
    // ---- epilogue ----
    int l4 = l >> 4, l15 = l & 15;
    #pragma unroll
    for (int q = 0; q < 4; ++q) {
        #pragma unroll
        for (int j = 0; j < 4; ++j) {
            int m = m0 + 16 * w + 4 * l4 + j;
            int n = n0 + 16 * q + l15;
            float val = acc[q][j];
            if (EOP == 0) {
                outF[(size_t)m * ldc + n] = val + bias[n];
            } else if (EOP == 1) {
                outB[(size_t)m * ldc + n] = f2bf(val + bias[n]);
            } else if (EOP == 2) {
                if (n < Ntot) {
                    int b = m & 63, tt = m >> 6;
                    bool act = tt < (lengths[b] - 1);
                    outF[((size_t)b * TM1 + tt) * VV + n] = act ? (val + bias[n]) : 0.f;
                }
            } else if (EOP == 3) {  // plain k-partials
                int mloc = m - m0;
                outF[((size_t)kz * 64 + mloc) * ldc + n] = val;
            } else {                // EOP == 4: gate-layout k-partials
                int col = 512 * q + (n0 >> 2) + l15;
                int mloc = m - m0;
                outF[((size_t)kz * 64 + mloc) * 2048 + col] = val;
            }
        }
    }
}

__global__ __launch_bounds__(256)
void kReduceHC(const float* __restrict__ Pc, const float* __restrict__ biasInit,
               float* __restrict__ hc, short* __restrict__ h16)
{
    int b = blockIdx.x, tid = threadIdx.x;
    for (int j = tid; j < 1024; j += 256) {
        float s = Pc[((size_t)0 * BB + b) * 1024 + j] + Pc[((size_t)1 * BB + b) * 1024 + j]
                + Pc[((size_t)2 * BB + b) * 1024 + j] + Pc[((size_t)3 * BB + b) * 1024 + j];
        s += biasInit[j];
        hc[b * 1024 + j] = s;
        if (j < 512) h16[b * 512 + j] = f2bf(s);
    }
}

// ---------------------------------------------------------------------------
// Fused Step B+C (512 blocks: b = blk&63, kc = blk>>6):
//   every block recomputes alpha for its b (cheap, deterministic, att1 L2-shared
//   across the 8 same-b blocks via blk&63 XCD mapping), then computes its
//   256-col awe slice + gate -> x16. out_alpha written by kc==0 blocks only.
// ---------------------------------------------------------------------------
template<int FULL>
__global__ __launch_bounds__(256)
void kStepBC(const short* __restrict__ att1, const float* __restrict__ P3h,
             const float* __restrict__ faw, const float* __restrict__ fab,
             const int* __restrict__ lengths, const void* __restrict__ encp,
             short* __restrict__ x16, float* __restrict__ alpha_out, int t)
{
    int blk = blockIdx.x, tid = threadIdx.x;
    int b = blk & 63, kc = blk >> 6;
    __shared__ float att2s[512];
    __shared__ float fw[512];
    __shared__ float es[PP];
    __shared__ float alps[PP];
    __shared__ float red[8];
    __shared__ float part[8][256];

    for (int a = tid; a < 512; a += 256) { att2s[a] = P3h[b * NCAT + a]; fw[a] = faw[a]; }
    __syncthreads();

    int wv = tid >> 6, lane = tid & 63;
    // e[p] = relu(att1[p]+att2).faw + fab
    for (int p = wv; p < PP; p += 4) {
        short8 v = *reinterpret_cast<const short8*>(&att1[((size_t)b * PP + p) * 512 + lane * 8]);
        float s = 0.f;
        #pragma unroll
        for (int j = 0; j < 8; ++j) {
            float x = bf2f(v[j]) + att2s[lane * 8 + j];
            s += fmaxf(x, 0.f) * fw[lane * 8 + j];
        }
        #pragma unroll
        for (int off = 32; off > 0; off >>= 1) s += __shfl_down(s, off, 64);
        if (lane == 0) es[p] = s + fab[0];
    }
    __syncthreads();
    // softmax over 196
    float m = -1e30f;
    for (int p = tid; p < PP; p += 256) m = fmaxf(m, es[p]);
    #pragma unroll
    for (int off = 32; off > 0; off >>= 1) m = fmaxf(m, __shfl_down(m, off, 64));
    if (lane == 0) red[wv] = m;
    __syncthreads();
    m = fmaxf(fmaxf(red[0], red[1]), fmaxf(red[2], red[3]));
    float ssum = 0.f;
    for (int p = tid; p < PP; p += 256) { float ev = __expf(es[p] - m); es[p] = ev; ssum += ev; }
    #pragma unroll
    for (int off = 32; off > 0; off >>= 1) ssum += __shfl_down(ssum, off, 64);
    if (lane == 0) red[4 + wv] = ssum;
    __syncthreads();
    float inv = 1.f / (red[4] + red[5] + red[6] + red[7]);
    bool active = t < (lengths[b] - 1);
    for (int p = tid; p < PP; p += 256) {
        float al = es[p] * inv;
        alps[p] = al;
        if (kc == 0)
            alpha_out[((size_t)b * TM1 + t) * PP + p] = active ? al : 0.f;
    }
    __syncthreads();

    // awe for 256-col slice [kc*256, kc*256+256)
    if (FULL) {
        const short* enc16 = (const short*)encp;
        int g = tid & 31, prow = tid >> 5;      // 8 cols/thread, 8 p-lanes
        int k0 = kc * 256 + g * 8;
        float acc[8] = {};
        for (int p = prow; p < PP; p += 8) {
            short8 v = *reinterpret_cast<const short8*>(&enc16[((size_t)b * PP + p) * CENC + k0]);
            float a_ = alps[p];
            #pragma unroll
            for (int j = 0; j < 8; ++j) acc[j] = fmaf(bf2f(v[j]), a_, acc[j]);
        }
        *reinterpret_cast<float4*>(&part[prow][g * 8])     = make_float4(acc[0], acc[1], acc[2], acc[3]);
        *reinterpret_cast<float4*>(&part[prow][g * 8 + 4]) = make_float4(acc[4], acc[5], acc[6], acc[7]);
        __syncthreads();
        int c = tid;
        float awe = 0.f;
        #pragma unroll
        for (int pr = 0; pr < 8; ++pr) awe += part[pr][c];
        int k = kc * 256 + c;
        float gate = 1.f / (1.f + __expf(-P3h[b * NCAT + 512 + k]));
        x16[(size_t)b * CENC + k] = f2bf(gate * awe);
    } else {
        const float* enc = (const float*)encp;
        int g = tid & 63, prow = tid >> 6;      // 4 cols/thread, 4 p-lanes
        int k0 = kc * 256 + g * 4;
        float acc[4] = {};
        for (int p = prow; p < PP; p += 4) {
            float4 v = *reinterpret_cast<const float4*>(&enc[((size_t)b * PP + p) * CENC + k0]);
            float a_ = alps[p];
            acc[0] = fmaf(v.x, a_, acc[0]); acc[1] = fmaf(v.y, a_, acc[1]);
            acc[2] = fmaf(v.z, a_, acc[2]); acc[3] = fmaf(v.w, a_, acc[3]);
        }
        *reinterpret_cast<float4*>(&part[prow][g * 4]) = make_float4(acc[0], acc[1], acc[2], acc[3]);
        __syncthreads();
        int c = tid;
        float awe = part[0][c] + part[1][c] + part[2][c] + part[3][c];
        int k = kc * 256 + c;
        float gate = 1.f / (1.f + __expf(-P3h[b * NCAT + 512 + k]));
        x16[(size_t)b * CENC + k] = f2bf(gate * awe);
    }
}

// ---------------------------------------------------------------------------
// Step D2: reduce gate partials (4 chunks) + emb part + Whh part; LSTM update.
// ---------------------------------------------------------------------------
__global__ __launch_bounds__(256)
void kStepD2(const float* __restrict__ Pg, const float* __restrict__ gates_emb,
             const float* __restrict__ P3h, float* __restrict__ hc,
             short* __restrict__ h16, short* __restrict__ allH, int t)
{
    int b = blockIdx.x, tid = threadIdx.x;
    for (int d = tid; d < 512; d += 256) {
        float g4[4];
        #pragma unroll
        for (int q = 0; q < 4; ++q) {
            int col = q * 512 + d;
            float s = gates_emb[((size_t)t * 64 + b) * 2048 + col] + P3h[b * NCAT + 2560 + col];
            #pragma unroll
            for (int kz = 0; kz < 4; ++kz) s += Pg[((size_t)kz * 64 + b) * 2048 + col];
            g4[q] = s;
        }
        float i_ = 1.f / (1.f + __expf(-g4[0]));
        float f_ = 1.f / (1.f + __expf(-g4[1]));
        float g_ = tanhf(g4[2]);
        float o_ = 1.f / (1.f + __expf(-g4[3]));
        float c_new = f_ * hc[b * 1024 + 512 + d] + i_ * g_;
        float h_new = o_ * tanhf(c_new);
        hc[b * 1024 + 512 + d] = c_new;
        hc[b * 1024 + d] = h_new;
        short hb = f2bf(h_new);
        h16[b * 512 + d] = hb;
        allH[((size_t)t * 64 + b) * 512 + d] = hb;
    }
}

extern "C" void kernel_launch(void* const* d_in, const int* in_sizes, int n_in,
                              void* d_out, int out_size, void* d_ws, size_t ws_size,
                              hipStream_t stream)
{
    const float* enc        = (const float*)d_in[0];
    const int*   captions   = (const int*)d_in[1];
    const int*   lengths    = (const int*)d_in[2];
    const float* enc_att_w  = (const float*)d_in[3];
    const float* enc_att_b  = (const float*)d_in[4];
    const float* hid_att_w  = (const float*)d_in[5];
    const float* hid_att_b  = (const float*)d_in[6];
    const float* full_att_w = (const float*)d_in[7];
    const float* full_att_b = (const float*)d_in[8];
    const float* embw       = (const float*)d_in[9];
    const float* w_ih       = (const float*)d_in[10];
    const float* w_hh       = (const float*)d_in[11];
    const float* b_ih       = (const float*)d_in[12];
    const float* b_hh       = (const float*)d_in[13];
    const float* init_h_w   = (const float*)d_in[14];
    const float* init_h_b   = (const float*)d_in[15];
    const float* init_c_w   = (const float*)d_in[16];
    const float* init_c_b   = (const float*)d_in[17];
    const float* fbeta_w    = (const float*)d_in[18];
    const float* fbeta_b    = (const float*)d_in[19];
    const float* fc_w       = (const float*)d_in[20];
    const float* fc_b       = (const float*)d_in[21];

    float* out_pred  = (float*)d_out;                        // [64][19][10000]
    float* out_alpha = out_pred + (size_t)BB * TM1 * VV;     // [64][19][196]

    // ---- scratch in d_out pred region (dead before pred GEMM)
    char* pr = (char*)d_out;
    short* att1_16   = (short*)pr;  pr += 12845056;  // live in loop
    float* gates_emb = (float*)pr;  pr += 9961472;   // live (overlaid at init)
    short* wcat16    = (short*)pr;  pr += 4718592;   // live [hid_att;fbeta;whh]
    short* wihe16    = (short*)pr;  pr += 8388608;   // live
    float* biascat   = (float*)pr;  pr += 18432;     // live (4608 f32)
    float* P3h       = (float*)pr;  pr += 1179648;   // live (loop)
    float* Pg        = (float*)pr;  pr += 2097152;   // live (loop)
    short* embA      = (short*)pr;  pr += 1245184;   // precompute only
    short* wihm16    = (short*)pr;  pr += 2097152;   // precompute only
    short* encw16    = (short*)pr;  pr += 2097152;   // dead after att1
    float* biasg     = (float*)pr;  pr += 8192;      // precompute only
    float* meanP     = (float*)pr;  pr += 3670016;   // dead after kReduceMean
    short* mean16    = (short*)pr;  pr += 262144;    // dead after init gemm

    // overlays (dead before their region's owner is written):
    short* initW16  = (short*)gates_emb;                      // 4.19MB
    float* biasInit = (float*)((char*)gates_emb + 4194304);   // 4KB
    float* hcP      = P3h;                                    // 1.0MB

    // ---- workspace
    char* wp = (char*)d_ws;
    float* hc    = (float*)wp;  wp += 262144;      // 64x1024 f32 (c in [:,512:])
    short* h16   = (short*)wp;  wp += 65536;       // 64x512 bf16
    short* x16   = (short*)wp;  wp += 262144;      // 64x2048 bf16
    short* fc16  = (short*)wp;  wp += 10240000;    // 10000x512 bf16
    short* allH  = (short*)wp;  wp += 1245184;     // 19x64x512 bf16
    short* enc16 = (short*)wp;  wp += 51380224;    // 64x196x2048 bf16 (optional)
    const bool full = ((size_t)(wp - (char*)d_ws) <= ws_size);

    // ---- precompute ----
    kPrepW<<<7752, 256, 0, stream>>>(enc_att_w, hid_att_w, fbeta_w, w_hh, w_ih, fc_w,
                                     init_h_w, init_c_w,
                                     hid_att_b, fbeta_b, b_ih, b_hh, init_h_b, init_c_b,
                                     encw16, wcat16, wihe16, wihm16, fc16, initW16,
                                     biascat, biasg, biasInit);
    if (full) kMeanEnc<1><<<dim3(64, 8, 7), 256, 0, stream>>>(enc, enc16, meanP);
    else      kMeanEnc<0><<<dim3(64, 8, 7), 256, 0, stream>>>(enc, enc16, meanP);
    kEmbGather<<<304, 256, 0, stream>>>(embw, captions, embA);
    kReduceMean<<<64, 256, 0, stream>>>(meanP, mean16);

    // h0|c0 partials = mean16 @ initW16^T  (MFMA, k-split x4) -> hcP
    kGemm<0, 0, 3, 0><<<dim3(16, 1, 4), 256, 0, stream>>>(mean16, CENC, initW16, CENC,
        nullptr, 1024, hcP, 1024, nullptr, 8, nullptr);
    kReduceHC<<<64, 256, 0, stream>>>(hcP, biasInit, hc, h16);

    // att1 = enc @ enc_att_w^T + b -> bf16 [12544][512]
    if (full)
        kGemm<0, 0, 1, 1><<<1568, 256, 0, stream>>>(enc16, CENC, encw16, CENC,
            enc_att_b, 512, nullptr, 512, att1_16, 32, nullptr);
    else
        kGemm<1, 0, 1, 1><<<1568, 256, 0, stream>>>(enc, CENC, encw16, CENC,
            enc_att_b, 512, nullptr, 512, att1_16, 32, nullptr);

    // gates_emb = embA @ W_ih[:, :512]^T + (b_ih + b_hh)  (overwrites initW16)
    kGemm<0, 0, 0, 0><<<dim3(32, 19, 1), 256, 0, stream>>>(embA, 512, wihm16, 512,
        biasg, 2048, gates_emb, 2048, nullptr, 8, nullptr);

    // ---- sequential decode: 4 kernels per step ----
    for (int t = 0; t < TM1; ++t) {
        // P3h = h @ [hid_att_w ; fbeta_w ; W_hh]^T + biascat  -> [64][4608]
        kGemm<0, 0, 0, 0><<<dim3(72, 1, 1), 256, 0, stream>>>(h16, 512, wcat16, 512,
            biascat, NCAT, P3h, NCAT, nullptr, 8, nullptr);

        if (full) kStepBC<1><<<512, 256, 0, stream>>>(att1_16, P3h, full_att_w,
            full_att_b, lengths, enc16, x16, out_alpha, t);
        else      kStepBC<0><<<512, 256, 0, stream>>>(att1_16, P3h, full_att_w,
            full_att_b, lengths, enc, x16, out_alpha, t);

        // gate partials: x @ W_ih[:, 512:]^T (gate-interleaved rows), k-split x4
        kGemm<0, 1, 4, 0><<<dim3(32, 1, 4), 256, 0, stream>>>(x16, CENC, wihe16, CENC,
            nullptr, 2048, Pg, 2048, nullptr, 8, nullptr);

        kStepD2<<<64, 256, 0, stream>>>(Pg, gates_emb, P3h, hc, h16, allH, t);
    }

    // ---- pred = allH @ fc_w^T + fc_b (masked, remapped) ----
    kGemm<0, 0, 2, 2><<<3040, 256, 0, stream>>>(allH, 512, fc16, 512,
        fc_b, VV, out_pred, VV, nullptr, 8, lengths);
}